// Round 6
// baseline (833.314 us; speedup 1.0000x reference)
//
#include <hip/hip_runtime.h>

#define N_V  20000
#define B_   8
#define F_   64
#define K_   6
#define OUT_ 64
#define NNZ_ 320000
#define BF   512    // B_*F_
#define NSLICE 8
#define SLICE_W 2500
#define NBUK (N_V * NSLICE)        // 160000 buckets
#define SCANB 157                  // ceil(NBUK/1024)

typedef unsigned short ushort_t;
typedef unsigned int   uint_t;

using frag_ab = __attribute__((ext_vector_type(8))) short;  // 8 bf16 (4 VGPRs)
using frag_cd = __attribute__((ext_vector_type(4))) float;  // 4 f32 acc

// ---- bf16 helpers ----
__device__ __forceinline__ ushort_t f2bf(float f) {          // round-to-nearest-even
    uint_t u = __float_as_uint(f);
    u += 0x7FFFu + ((u >> 16) & 1u);
    return (ushort_t)(u >> 16);
}
__device__ __forceinline__ uint_t pack2(float lo, float hi) {
    return (uint_t)f2bf(lo) | ((uint_t)f2bf(hi) << 16);
}
__device__ __forceinline__ void unpack2(uint_t u, float& lo, float& hi) {
    lo = __uint_as_float(u << 16);
    hi = __uint_as_float(u & 0xFFFF0000u);
}
__device__ __forceinline__ void unpack8(uint4 u, float* e) {
    unpack2(u.x, e[0], e[1]); unpack2(u.y, e[2], e[3]);
    unpack2(u.z, e[4], e[5]); unpack2(u.w, e[6], e[7]);
}

// ---------------- bucketed CSR build: key = slice*N_V + row (slice-major) ----------------
// Slice-major => a wave's 4 consecutive rows in one slice are ONE contiguous edge range.

__global__ void hist_kernel(const int* __restrict__ rows, const int* __restrict__ cols,
                            int* __restrict__ counts) {
    int e = blockIdx.x * 256 + threadIdx.x;
    if (e < NNZ_) {
        int key = (cols[e] / SLICE_W) * N_V + rows[e];
        atomicAdd(&counts[key], 1);
    }
}

__global__ __launch_bounds__(1024) void scan1(const int* __restrict__ counts,
                                              int* __restrict__ incl, int* __restrict__ bsum) {
    __shared__ int buf[1024];
    int tid = threadIdx.x;
    int i = blockIdx.x * 1024 + tid;
    int c = (i < NBUK) ? counts[i] : 0;
    buf[tid] = c;
    __syncthreads();
    for (int off = 1; off < 1024; off <<= 1) {
        int t = buf[tid];
        int add = (tid >= off) ? buf[tid - off] : 0;
        __syncthreads();
        buf[tid] = t + add;
        __syncthreads();
    }
    if (i < NBUK) incl[i] = buf[tid];
    if (tid == 1023) bsum[blockIdx.x] = buf[1023];
}

__global__ __launch_bounds__(256) void scan2(int* __restrict__ bsum) {
    __shared__ int buf[256];
    int tid = threadIdx.x;
    int c = (tid < SCANB) ? bsum[tid] : 0;
    buf[tid] = c;
    __syncthreads();
    for (int off = 1; off < 256; off <<= 1) {
        int t = buf[tid];
        int add = (tid >= off) ? buf[tid - off] : 0;
        __syncthreads();
        buf[tid] = t + add;
        __syncthreads();
    }
    if (tid < SCANB) bsum[tid] = buf[tid] - c;   // exclusive block offsets
}

__global__ __launch_bounds__(1024) void scan3(const int* __restrict__ counts,
                                              const int* __restrict__ bsum,
                                              int* __restrict__ bp, int* __restrict__ cursor) {
    int tid = threadIdx.x;
    int i = blockIdx.x * 1024 + tid;
    if (i < NBUK) {
        int p = bsum[blockIdx.x] + cursor[i];   // global inclusive prefix
        bp[i + 1] = p;
        cursor[i] = p - counts[i];              // bucket start for scatter
    }
    if (i == 0) bp[0] = 0;
}

// edges packed: {col | (row&3)<<28, val_bits}
__global__ void scatter_kernel(const int* __restrict__ rows, const int* __restrict__ cols,
                               const float* __restrict__ vals, int* __restrict__ cursor,
                               int2* __restrict__ edges) {
    int e = blockIdx.x * 256 + threadIdx.x;
    if (e < NNZ_) {
        int c = cols[e];
        int r = rows[e];
        int key = (c / SLICE_W) * N_V + r;
        int pos = atomicAdd(&cursor[key], 1);
        int2 pe;
        pe.x = c | ((r & 3) << 28);
        pe.y = __float_as_int(vals[e]);
        edges[pos] = pe;
    }
}

// ---------------- fat prep: x->X0 bf16 (T layout) + Wfrag pack ----------------
__global__ void prep_kernel(const float* __restrict__ x, uint_t* __restrict__ X0,
                            const float* __restrict__ W, ushort_t* __restrict__ Wfrag) {
    int blk = blockIdx.x;
    if (blk < 20000) {
        int idx = blk * 256 + threadIdx.x;      // over N_V*B_*32
        int f2 = idx & 31;
        int b  = (idx >> 5) & 7;
        int n  = idx >> 8;
        float2 v = *(const float2*)&x[((size_t)b * N_V + n) * F_ + f2 * 2];
        X0[n * 256 + b * 32 + f2] = pack2(v.x, v.y);
    } else {
        int idx = (blk - 20000) * 256 + threadIdx.x;
        if (idx < 12 * 4 * 64 * 8) {
            int j    = idx & 7;
            int lane = (idx >> 3) & 63;
            int ct   = (idx >> 9) & 3;
            int s    = idx >> 11;
            int o     = ct * 16 + (lane & 15);
            int kglob = s * 32 + ((lane >> 4) & 3) * 8 + j;
            Wfrag[idx] = f2bf(W[o * (K_ * F_) + kglob]);
        }
    }
}

// ---------------- column-phased SpMM, joint 4-row edge stream, ILP 4 ----------------
__device__ __forceinline__ void accum_edge(float acc[4][8], int rr_v, float v, uint4 u) {
    int rr = __builtin_amdgcn_readfirstlane(rr_v);   // wave-uniform scalar branch
    float e[8];
    unpack8(u, e);
    if (rr == 0) {
#pragma unroll
        for (int i = 0; i < 8; ++i) acc[0][i] = fmaf(v, e[i], acc[0][i]);
    } else if (rr == 1) {
#pragma unroll
        for (int i = 0; i < 8; ++i) acc[1][i] = fmaf(v, e[i], acc[1][i]);
    } else if (rr == 2) {
#pragma unroll
        for (int i = 0; i < 8; ++i) acc[2][i] = fmaf(v, e[i], acc[2][i]);
    } else {
#pragma unroll
        for (int i = 0; i < 8; ++i) acc[3][i] = fmaf(v, e[i], acc[3][i]);
    }
}

template <bool RECUR>
__global__ __launch_bounds__(256) void cheb_phase(const int* __restrict__ bp,
                                                  const int2* __restrict__ edges,
                                                  const ushort_t* __restrict__ Tprev,
                                                  const ushort_t* __restrict__ Tpp,
                                                  ushort_t* __restrict__ Tout) {
    const int wave = threadIdx.x >> 6, lane = threadIdx.x & 63;
    const int n0 = blockIdx.x * 16 + wave * 4;     // wave owns rows n0..n0+3 (n0 % 4 == 0)
    float acc[4][8];
#pragma unroll
    for (int r = 0; r < 4; ++r)
#pragma unroll
        for (int i = 0; i < 8; ++i) acc[r][i] = 0.f;

    for (int s = 0; s < NSLICE; ++s) {
        const int st = bp[s * N_V + n0];
        const int en = bp[s * N_V + n0 + 4];       // contiguous range for 4 rows in slice s
        for (int j = st; j < en; j += 4) {
            const int j1 = min(j + 1, en - 1);
            const int j2 = min(j + 2, en - 1);
            const int j3 = min(j + 3, en - 1);
            int2 e0 = edges[j];
            int2 e1 = edges[j1];
            int2 e2 = edges[j2];
            int2 e3 = edges[j3];
            float v0 = __int_as_float(e0.y);
            float v1 = (j + 1 < en) ? __int_as_float(e1.y) : 0.f;
            float v2 = (j + 2 < en) ? __int_as_float(e2.y) : 0.f;
            float v3 = (j + 3 < en) ? __int_as_float(e3.y) : 0.f;
            uint4 u0 = *(const uint4*)(Tprev + (size_t)(e0.x & 0xFFFFFFF) * BF + lane * 8);
            uint4 u1 = *(const uint4*)(Tprev + (size_t)(e1.x & 0xFFFFFFF) * BF + lane * 8);
            uint4 u2 = *(const uint4*)(Tprev + (size_t)(e2.x & 0xFFFFFFF) * BF + lane * 8);
            uint4 u3 = *(const uint4*)(Tprev + (size_t)(e3.x & 0xFFFFFFF) * BF + lane * 8);
            accum_edge(acc, e0.x >> 28, v0, u0);
            accum_edge(acc, e1.x >> 28, v1, u1);
            accum_edge(acc, e2.x >> 28, v2, u2);
            accum_edge(acc, e3.x >> 28, v3, u3);
        }
    }

#pragma unroll
    for (int r = 0; r < 4; ++r) {
        const int n = n0 + r;
        float res[8];
        if (RECUR) {
            uint4 up = *(const uint4*)(Tpp + (size_t)n * BF + lane * 8);
            float ep[8];
            unpack8(up, ep);
#pragma unroll
            for (int i = 0; i < 8; ++i) res[i] = 2.f * acc[r][i] - ep[i];
        } else {
#pragma unroll
            for (int i = 0; i < 8; ++i) res[i] = acc[r][i];
        }
        uint4 st4;
        st4.x = pack2(res[0], res[1]);
        st4.y = pack2(res[2], res[3]);
        st4.z = pack2(res[4], res[5]);
        st4.w = pack2(res[6], res[7]);
        *(uint4*)(Tout + (size_t)n * BF + lane * 8) = st4;
    }
}

// ---------------- FC via MFMA 16x16x32 bf16, 2 tiles/wave ----------------
__global__ __launch_bounds__(256) void fc_mfma(const ushort_t* __restrict__ X0,
                                               const ushort_t* __restrict__ T1,
                                               const ushort_t* __restrict__ T2,
                                               const ushort_t* __restrict__ T3,
                                               const ushort_t* __restrict__ T4,
                                               const ushort_t* __restrict__ T5,
                                               const ushort_t* __restrict__ Wfrag,
                                               const float* __restrict__ bias,
                                               float* __restrict__ out) {
    const int wave = threadIdx.x >> 6, lane = threadIdx.x & 63;
    const int quad = lane >> 4, col = lane & 15;
    const int tb = blockIdx.x * 128 + wave * 32;      // 2 tiles: tb, tb+16
    const int r0 = tb + col, r1 = tb + 16 + col;
    const ushort_t* Tbuf[6] = {X0, T1, T2, T3, T4, T5};

    frag_cd acc0[4], acc1[4];
#pragma unroll
    for (int ct = 0; ct < 4; ++ct) {
        acc0[ct] = (frag_cd){0.f, 0.f, 0.f, 0.f};
        acc1[ct] = (frag_cd){0.f, 0.f, 0.f, 0.f};
    }

#pragma unroll
    for (int s = 0; s < 12; ++s) {
        const int f0 = (s & 1) * 32 + quad * 8;
        frag_ab a0 = *(const frag_ab*)(Tbuf[s >> 1] + (size_t)r0 * F_ + f0);
        frag_ab a1 = *(const frag_ab*)(Tbuf[s >> 1] + (size_t)r1 * F_ + f0);
#pragma unroll
        for (int ct = 0; ct < 4; ++ct) {
            frag_ab bfr = *(const frag_ab*)(Wfrag + (((s * 4 + ct) * 64 + lane) << 3));
            acc0[ct] = __builtin_amdgcn_mfma_f32_16x16x32_bf16(a0, bfr, acc0[ct], 0, 0, 0);
            acc1[ct] = __builtin_amdgcn_mfma_f32_16x16x32_bf16(a1, bfr, acc1[ct], 0, 0, 0);
        }
    }

    // C/D: col = lane&15, row = quad*4 + reg
#pragma unroll
    for (int ct = 0; ct < 4; ++ct) {
        const int o = ct * 16 + col;
        const float bv = bias[o];
#pragma unroll
        for (int reg = 0; reg < 4; ++reg) {
            int ra = tb + quad * 4 + reg;
            int rb = ra + 16;
            out[(size_t)(ra & 7) * N_V * OUT_ + (size_t)(ra >> 3) * OUT_ + o] = acc0[ct][reg] + bv;
            out[(size_t)(rb & 7) * N_V * OUT_ + (size_t)(rb >> 3) * OUT_ + o] = acc1[ct][reg] + bv;
        }
    }
}

// ---------------- launcher ----------------

extern "C" void kernel_launch(void* const* d_in, const int* in_sizes, int n_in,
                              void* d_out, int out_size, void* d_ws, size_t ws_size,
                              hipStream_t stream) {
    const float* x    = (const float*)d_in[0];
    const int*   rows = (const int*)  d_in[1];
    const int*   cols = (const int*)  d_in[2];
    const float* vals = (const float*)d_in[3];
    const float* W    = (const float*)d_in[4];
    const float* bias = (const float*)d_in[5];
    float* out = (float*)d_out;

    const size_t TSZ = (size_t)N_V * BF;           // bf16 elements per T buffer
    ushort_t* T1 = (ushort_t*)d_ws;
    ushort_t* T2 = T1 + TSZ;
    ushort_t* T3 = T2 + TSZ;
    ushort_t* T4 = T3 + TSZ;
    ushort_t* T5 = T4 + TSZ;
    ushort_t* X0 = T5 + TSZ;
    ushort_t* Wfrag = X0 + TSZ;                    // 24576 ushorts
    int* counts    = (int*)(Wfrag + 24576);        // NBUK
    int* bp        = counts + NBUK;                // NBUK+1 (+pad)
    int* cursor    = bp + NBUK + 64;               // NBUK
    int* bsum      = cursor + NBUK;                // 256
    int2* edges    = (int2*)(bsum + 256);          // NNZ int2

    hipMemsetAsync(counts, 0, NBUK * sizeof(int), stream);
    hist_kernel<<<(NNZ_ + 255) / 256, 256, 0, stream>>>(rows, cols, counts);
    scan1<<<SCANB, 1024, 0, stream>>>(counts, cursor, bsum);
    scan2<<<1, 256, 0, stream>>>(bsum);
    scan3<<<SCANB, 1024, 0, stream>>>(counts, bsum, bp, cursor);
    scatter_kernel<<<(NNZ_ + 255) / 256, 256, 0, stream>>>(rows, cols, vals, cursor, edges);
    prep_kernel<<<20096, 256, 0, stream>>>(x, (uint_t*)X0, W, Wfrag);

    cheb_phase<false><<<N_V / 16, 256, 0, stream>>>(bp, edges, X0, nullptr, T1);
    cheb_phase<true ><<<N_V / 16, 256, 0, stream>>>(bp, edges, T1, X0, T2);
    cheb_phase<true ><<<N_V / 16, 256, 0, stream>>>(bp, edges, T2, T1, T3);
    cheb_phase<true ><<<N_V / 16, 256, 0, stream>>>(bp, edges, T3, T2, T4);
    cheb_phase<true ><<<N_V / 16, 256, 0, stream>>>(bp, edges, T4, T3, T5);

    fc_mfma<<<(N_V * B_) / 128, 256, 0, stream>>>(X0, T1, T2, T3, T4, T5, Wfrag, bias, out);
}

// Round 7
// 393.024 us; speedup vs baseline: 2.1203x; 2.1203x over previous
//
#include <hip/hip_runtime.h>

#define N_V  20000
#define B_   8
#define F_   64
#define K_   6
#define OUT_ 64
#define NNZ_ 320000
#define BF   512    // B_*F_
#define NSLICE 8
#define SLICE_W 2500
#define NBUK (N_V * NSLICE)        // 160000 buckets
#define SCANB 157                  // ceil(NBUK/1024)

typedef unsigned short ushort_t;
typedef unsigned int   uint_t;

using frag_ab = __attribute__((ext_vector_type(8))) short;  // 8 bf16 (4 VGPRs)
using frag_cd = __attribute__((ext_vector_type(4))) float;  // 4 f32 acc

// ---- bf16 helpers ----
__device__ __forceinline__ ushort_t f2bf(float f) {          // round-to-nearest-even
    uint_t u = __float_as_uint(f);
    u += 0x7FFFu + ((u >> 16) & 1u);
    return (ushort_t)(u >> 16);
}
__device__ __forceinline__ uint_t pack2(float lo, float hi) {
    return (uint_t)f2bf(lo) | ((uint_t)f2bf(hi) << 16);
}
__device__ __forceinline__ void unpack2(uint_t u, float& lo, float& hi) {
    lo = __uint_as_float(u << 16);
    hi = __uint_as_float(u & 0xFFFF0000u);
}

// ---------------- bucketed CSR build: key = slice*N_V + row (slice-major) ----------------
// A wave's 2 consecutive rows in one slice are ONE contiguous edge range.

__global__ void hist_kernel(const int* __restrict__ rows, const int* __restrict__ cols,
                            int* __restrict__ counts) {
    int e = blockIdx.x * 256 + threadIdx.x;
    if (e < NNZ_) {
        int key = (cols[e] / SLICE_W) * N_V + rows[e];
        atomicAdd(&counts[key], 1);
    }
}

__global__ __launch_bounds__(1024) void scan1(const int* __restrict__ counts,
                                              int* __restrict__ incl, int* __restrict__ bsum) {
    __shared__ int buf[1024];
    int tid = threadIdx.x;
    int i = blockIdx.x * 1024 + tid;
    int c = (i < NBUK) ? counts[i] : 0;
    buf[tid] = c;
    __syncthreads();
    for (int off = 1; off < 1024; off <<= 1) {
        int t = buf[tid];
        int add = (tid >= off) ? buf[tid - off] : 0;
        __syncthreads();
        buf[tid] = t + add;
        __syncthreads();
    }
    if (i < NBUK) incl[i] = buf[tid];
    if (tid == 1023) bsum[blockIdx.x] = buf[1023];
}

__global__ __launch_bounds__(256) void scan2(int* __restrict__ bsum) {
    __shared__ int buf[256];
    int tid = threadIdx.x;
    int c = (tid < SCANB) ? bsum[tid] : 0;
    buf[tid] = c;
    __syncthreads();
    for (int off = 1; off < 256; off <<= 1) {
        int t = buf[tid];
        int add = (tid >= off) ? buf[tid - off] : 0;
        __syncthreads();
        buf[tid] = t + add;
        __syncthreads();
    }
    if (tid < SCANB) bsum[tid] = buf[tid] - c;   // exclusive block offsets
}

__global__ __launch_bounds__(1024) void scan3(const int* __restrict__ counts,
                                              const int* __restrict__ bsum,
                                              int* __restrict__ bp, int* __restrict__ cursor) {
    int tid = threadIdx.x;
    int i = blockIdx.x * 1024 + tid;
    if (i < NBUK) {
        int p = bsum[blockIdx.x] + cursor[i];   // global inclusive prefix
        bp[i + 1] = p;
        cursor[i] = p - counts[i];              // bucket start for scatter
    }
    if (i == 0) bp[0] = 0;
}

// edges packed: {col, val_bits}
__global__ void scatter_kernel(const int* __restrict__ rows, const int* __restrict__ cols,
                               const float* __restrict__ vals, int* __restrict__ cursor,
                               int2* __restrict__ edges) {
    int e = blockIdx.x * 256 + threadIdx.x;
    if (e < NNZ_) {
        int c = cols[e];
        int key = (c / SLICE_W) * N_V + rows[e];
        int pos = atomicAdd(&cursor[key], 1);
        int2 pe;
        pe.x = c;
        pe.y = __float_as_int(vals[e]);
        edges[pos] = pe;
    }
}

// ---------------- fat prep: x->X0 bf16 (T layout) + Wfrag pack ----------------
__global__ void prep_kernel(const float* __restrict__ x, uint_t* __restrict__ X0,
                            const float* __restrict__ W, ushort_t* __restrict__ Wfrag) {
    int blk = blockIdx.x;
    if (blk < 20000) {
        int idx = blk * 256 + threadIdx.x;      // over N_V*B_*32
        int f2 = idx & 31;
        int b  = (idx >> 5) & 7;
        int n  = idx >> 8;
        float2 v = *(const float2*)&x[((size_t)b * N_V + n) * F_ + f2 * 2];
        X0[n * 256 + b * 32 + f2] = pack2(v.x, v.y);
    } else {
        int idx = (blk - 20000) * 256 + threadIdx.x;
        if (idx < 12 * 4 * 64 * 8) {
            int j    = idx & 7;
            int lane = (idx >> 3) & 63;
            int ct   = (idx >> 9) & 3;
            int s    = idx >> 11;
            int o     = ct * 16 + (lane & 15);
            int kglob = s * 32 + ((lane >> 4) & 3) * 8 + j;
            Wfrag[idx] = f2bf(W[o * (K_ * F_) + kglob]);
        }
    }
}

// ---------------- column-phased SpMM: 2 rows/wave, split-point predication ----------------
template <bool RECUR>
__global__ __launch_bounds__(256) void cheb_phase(const int* __restrict__ bp,
                                                  const int2* __restrict__ edges,
                                                  const ushort_t* __restrict__ Tprev,
                                                  const ushort_t* __restrict__ Tpp,
                                                  ushort_t* __restrict__ Tout) {
    const int wave = threadIdx.x >> 6, lane = threadIdx.x & 63;
    const int n0 = blockIdx.x * 8 + wave * 2;      // 2 rows per wave
    const int fo = lane * 8;                        // bf16 offset (16B per lane)

    float a0[8], a1[8];
#pragma unroll
    for (int i = 0; i < 8; ++i) { a0[i] = 0.f; a1[i] = 0.f; }

    for (int s = 0; s < NSLICE; ++s) {
        const int base = s * N_V + n0;
        const int st  = bp[base];
        const int mid = bp[base + 1];
        const int en  = bp[base + 2];
        for (int j = st; j < en; j += 4) {
            const int j1 = j + 1, j2 = j + 2, j3 = j + 3;
            const int c1 = min(j1, en - 1), c2 = min(j2, en - 1), c3 = min(j3, en - 1);
            int2 E0 = edges[j];
            int2 E1 = edges[c1];
            int2 E2 = edges[c2];
            int2 E3 = edges[c3];
            float v0 = __int_as_float(E0.y);
            float v1 = (j1 < en) ? __int_as_float(E1.y) : 0.f;
            float v2 = (j2 < en) ? __int_as_float(E2.y) : 0.f;
            float v3 = (j3 < en) ? __int_as_float(E3.y) : 0.f;
            uint4 u0 = *(const uint4*)(Tprev + (size_t)E0.x * BF + fo);
            uint4 u1 = *(const uint4*)(Tprev + (size_t)E1.x * BF + fo);
            uint4 u2 = *(const uint4*)(Tprev + (size_t)E2.x * BF + fo);
            uint4 u3 = *(const uint4*)(Tprev + (size_t)E3.x * BF + fo);
            float p00 = (j  < mid) ? v0 : 0.f, p01 = (j  < mid) ? 0.f : v0;
            float p10 = (j1 < mid) ? v1 : 0.f, p11 = (j1 < mid) ? 0.f : v1;
            float p20 = (j2 < mid) ? v2 : 0.f, p21 = (j2 < mid) ? 0.f : v2;
            float p30 = (j3 < mid) ? v3 : 0.f, p31 = (j3 < mid) ? 0.f : v3;
            float e0[8], e1[8], e2[8], e3[8];
            unpack2(u0.x, e0[0], e0[1]); unpack2(u0.y, e0[2], e0[3]);
            unpack2(u0.z, e0[4], e0[5]); unpack2(u0.w, e0[6], e0[7]);
            unpack2(u1.x, e1[0], e1[1]); unpack2(u1.y, e1[2], e1[3]);
            unpack2(u1.z, e1[4], e1[5]); unpack2(u1.w, e1[6], e1[7]);
            unpack2(u2.x, e2[0], e2[1]); unpack2(u2.y, e2[2], e2[3]);
            unpack2(u2.z, e2[4], e2[5]); unpack2(u2.w, e2[6], e2[7]);
            unpack2(u3.x, e3[0], e3[1]); unpack2(u3.y, e3[2], e3[3]);
            unpack2(u3.z, e3[4], e3[5]); unpack2(u3.w, e3[6], e3[7]);
#pragma unroll
            for (int i = 0; i < 8; ++i) {
                a0[i] = fmaf(p00, e0[i], a0[i]);
                a1[i] = fmaf(p01, e0[i], a1[i]);
                a0[i] = fmaf(p10, e1[i], a0[i]);
                a1[i] = fmaf(p11, e1[i], a1[i]);
                a0[i] = fmaf(p20, e2[i], a0[i]);
                a1[i] = fmaf(p21, e2[i], a1[i]);
                a0[i] = fmaf(p30, e3[i], a0[i]);
                a1[i] = fmaf(p31, e3[i], a1[i]);
            }
        }
    }

    // epilogue: row n0 from a0, row n0+1 from a1
    {
        float res[8];
#pragma unroll
        for (int i = 0; i < 8; ++i) res[i] = a0[i];
        if (RECUR) {
            uint4 up = *(const uint4*)(Tpp + (size_t)n0 * BF + fo);
            float ep[8];
            unpack2(up.x, ep[0], ep[1]); unpack2(up.y, ep[2], ep[3]);
            unpack2(up.z, ep[4], ep[5]); unpack2(up.w, ep[6], ep[7]);
#pragma unroll
            for (int i = 0; i < 8; ++i) res[i] = 2.f * res[i] - ep[i];
        }
        uint4 st4;
        st4.x = pack2(res[0], res[1]);
        st4.y = pack2(res[2], res[3]);
        st4.z = pack2(res[4], res[5]);
        st4.w = pack2(res[6], res[7]);
        *(uint4*)(Tout + (size_t)n0 * BF + fo) = st4;
    }
    {
        float res[8];
#pragma unroll
        for (int i = 0; i < 8; ++i) res[i] = a1[i];
        if (RECUR) {
            uint4 up = *(const uint4*)(Tpp + (size_t)(n0 + 1) * BF + fo);
            float ep[8];
            unpack2(up.x, ep[0], ep[1]); unpack2(up.y, ep[2], ep[3]);
            unpack2(up.z, ep[4], ep[5]); unpack2(up.w, ep[6], ep[7]);
#pragma unroll
            for (int i = 0; i < 8; ++i) res[i] = 2.f * res[i] - ep[i];
        }
        uint4 st4;
        st4.x = pack2(res[0], res[1]);
        st4.y = pack2(res[2], res[3]);
        st4.z = pack2(res[4], res[5]);
        st4.w = pack2(res[6], res[7]);
        *(uint4*)(Tout + (size_t)(n0 + 1) * BF + fo) = st4;
    }
}

// ---------------- FC via MFMA 16x16x32 bf16, 2 tiles/wave ----------------
__global__ __launch_bounds__(256) void fc_mfma(const ushort_t* __restrict__ X0,
                                               const ushort_t* __restrict__ T1,
                                               const ushort_t* __restrict__ T2,
                                               const ushort_t* __restrict__ T3,
                                               const ushort_t* __restrict__ T4,
                                               const ushort_t* __restrict__ T5,
                                               const ushort_t* __restrict__ Wfrag,
                                               const float* __restrict__ bias,
                                               float* __restrict__ out) {
    const int wave = threadIdx.x >> 6, lane = threadIdx.x & 63;
    const int quad = lane >> 4, col = lane & 15;
    const int tb = blockIdx.x * 128 + wave * 32;      // 2 tiles: tb, tb+16
    const int r0 = tb + col, r1 = tb + 16 + col;
    const ushort_t* Tbuf[6] = {X0, T1, T2, T3, T4, T5};

    frag_cd acc0[4], acc1[4];
#pragma unroll
    for (int ct = 0; ct < 4; ++ct) {
        acc0[ct] = (frag_cd){0.f, 0.f, 0.f, 0.f};
        acc1[ct] = (frag_cd){0.f, 0.f, 0.f, 0.f};
    }

#pragma unroll
    for (int s = 0; s < 12; ++s) {
        const int f0 = (s & 1) * 32 + quad * 8;
        frag_ab fa0 = *(const frag_ab*)(Tbuf[s >> 1] + (size_t)r0 * F_ + f0);
        frag_ab fa1 = *(const frag_ab*)(Tbuf[s >> 1] + (size_t)r1 * F_ + f0);
#pragma unroll
        for (int ct = 0; ct < 4; ++ct) {
            frag_ab bfr = *(const frag_ab*)(Wfrag + (((s * 4 + ct) * 64 + lane) << 3));
            acc0[ct] = __builtin_amdgcn_mfma_f32_16x16x32_bf16(fa0, bfr, acc0[ct], 0, 0, 0);
            acc1[ct] = __builtin_amdgcn_mfma_f32_16x16x32_bf16(fa1, bfr, acc1[ct], 0, 0, 0);
        }
    }

    // C/D: col = lane&15, row = quad*4 + reg
#pragma unroll
    for (int ct = 0; ct < 4; ++ct) {
        const int o = ct * 16 + col;
        const float bv = bias[o];
#pragma unroll
        for (int reg = 0; reg < 4; ++reg) {
            int ra = tb + quad * 4 + reg;
            int rb = ra + 16;
            out[(size_t)(ra & 7) * N_V * OUT_ + (size_t)(ra >> 3) * OUT_ + o] = acc0[ct][reg] + bv;
            out[(size_t)(rb & 7) * N_V * OUT_ + (size_t)(rb >> 3) * OUT_ + o] = acc1[ct][reg] + bv;
        }
    }
}

// ---------------- launcher ----------------

extern "C" void kernel_launch(void* const* d_in, const int* in_sizes, int n_in,
                              void* d_out, int out_size, void* d_ws, size_t ws_size,
                              hipStream_t stream) {
    const float* x    = (const float*)d_in[0];
    const int*   rows = (const int*)  d_in[1];
    const int*   cols = (const int*)  d_in[2];
    const float* vals = (const float*)d_in[3];
    const float* W    = (const float*)d_in[4];
    const float* bias = (const float*)d_in[5];
    float* out = (float*)d_out;

    const size_t TSZ = (size_t)N_V * BF;           // bf16 elements per T buffer
    ushort_t* T1 = (ushort_t*)d_ws;
    ushort_t* T2 = T1 + TSZ;
    ushort_t* T3 = T2 + TSZ;
    ushort_t* T4 = T3 + TSZ;
    ushort_t* T5 = T4 + TSZ;
    ushort_t* X0 = T5 + TSZ;
    ushort_t* Wfrag = X0 + TSZ;                    // 24576 ushorts
    int* counts    = (int*)(Wfrag + 24576);        // NBUK
    int* bp        = counts + NBUK;                // NBUK+1 (+pad)
    int* cursor    = bp + NBUK + 64;               // NBUK
    int* bsum      = cursor + NBUK;                // 256
    int2* edges    = (int2*)(bsum + 256);          // NNZ int2

    hipMemsetAsync(counts, 0, NBUK * sizeof(int), stream);
    hist_kernel<<<(NNZ_ + 255) / 256, 256, 0, stream>>>(rows, cols, counts);
    scan1<<<SCANB, 1024, 0, stream>>>(counts, cursor, bsum);
    scan2<<<1, 256, 0, stream>>>(bsum);
    scan3<<<SCANB, 1024, 0, stream>>>(counts, bsum, bp, cursor);
    scatter_kernel<<<(NNZ_ + 255) / 256, 256, 0, stream>>>(rows, cols, vals, cursor, edges);
    prep_kernel<<<20096, 256, 0, stream>>>(x, (uint_t*)X0, W, Wfrag);

    cheb_phase<false><<<N_V / 8, 256, 0, stream>>>(bp, edges, X0, nullptr, T1);
    cheb_phase<true ><<<N_V / 8, 256, 0, stream>>>(bp, edges, T1, X0, T2);
    cheb_phase<true ><<<N_V / 8, 256, 0, stream>>>(bp, edges, T2, T1, T3);
    cheb_phase<true ><<<N_V / 8, 256, 0, stream>>>(bp, edges, T3, T2, T4);
    cheb_phase<true ><<<N_V / 8, 256, 0, stream>>>(bp, edges, T4, T3, T5);

    fc_mfma<<<(N_V * B_) / 128, 256, 0, stream>>>(X0, T1, T2, T3, T4, T5, Wfrag, bias, out);
}

// Round 8
// 388.713 us; speedup vs baseline: 2.1438x; 1.0111x over previous
//
#include <hip/hip_runtime.h>

#define N_V  20000
#define B_   8
#define F_   64
#define K_   6
#define OUT_ 64
#define NNZ_ 320000
#define BF   512    // B_*F_
#define NSLICE 8
#define SLICE_W 2500
#define NPAIR (N_V / 2)            // 10000 row pairs
#define NBUK (NPAIR * NSLICE)      // 80000 buckets
#define SCANB 79                   // ceil(NBUK/1024)

typedef unsigned short ushort_t;
typedef unsigned int   uint_t;

using frag_ab = __attribute__((ext_vector_type(8))) short;  // 8 bf16 (4 VGPRs)
using frag_cd = __attribute__((ext_vector_type(4))) float;  // 4 f32 acc

// ---- bf16 helpers ----
__device__ __forceinline__ ushort_t f2bf(float f) {          // round-to-nearest-even
    uint_t u = __float_as_uint(f);
    u += 0x7FFFu + ((u >> 16) & 1u);
    return (ushort_t)(u >> 16);
}
__device__ __forceinline__ uint_t pack2(float lo, float hi) {
    return (uint_t)f2bf(lo) | ((uint_t)f2bf(hi) << 16);
}
__device__ __forceinline__ void unpack2(uint_t u, float& lo, float& hi) {
    lo = __uint_as_float(u << 16);
    hi = __uint_as_float(u & 0xFFFF0000u);
}

// -------- bucketed build: key = (row/2)*8 + col/2500 (pair-major, slice-ordered) --------
// Each wave (one row pair) gets ONE contiguous, slice-ordered edge stream (~32 edges).

__global__ void hist_kernel(const int* __restrict__ rows, const int* __restrict__ cols,
                            int* __restrict__ counts) {
    int e = blockIdx.x * 256 + threadIdx.x;
    if (e < NNZ_) {
        int key = (rows[e] >> 1) * NSLICE + cols[e] / SLICE_W;
        atomicAdd(&counts[key], 1);
    }
}

__global__ __launch_bounds__(1024) void scan1(const int* __restrict__ counts,
                                              int* __restrict__ incl, int* __restrict__ bsum) {
    __shared__ int buf[1024];
    int tid = threadIdx.x;
    int i = blockIdx.x * 1024 + tid;
    int c = (i < NBUK) ? counts[i] : 0;
    buf[tid] = c;
    __syncthreads();
    for (int off = 1; off < 1024; off <<= 1) {
        int t = buf[tid];
        int add = (tid >= off) ? buf[tid - off] : 0;
        __syncthreads();
        buf[tid] = t + add;
        __syncthreads();
    }
    if (i < NBUK) incl[i] = buf[tid];
    if (tid == 1023) bsum[blockIdx.x] = buf[1023];
}

__global__ __launch_bounds__(256) void scan2(int* __restrict__ bsum) {
    __shared__ int buf[256];
    int tid = threadIdx.x;
    int c = (tid < SCANB) ? bsum[tid] : 0;
    buf[tid] = c;
    __syncthreads();
    for (int off = 1; off < 256; off <<= 1) {
        int t = buf[tid];
        int add = (tid >= off) ? buf[tid - off] : 0;
        __syncthreads();
        buf[tid] = t + add;
        __syncthreads();
    }
    if (tid < SCANB) bsum[tid] = buf[tid] - c;   // exclusive block offsets
}

__global__ __launch_bounds__(1024) void scan3(const int* __restrict__ counts,
                                              const int* __restrict__ bsum,
                                              int* __restrict__ bp, int* __restrict__ cursor) {
    int tid = threadIdx.x;
    int i = blockIdx.x * 1024 + tid;
    if (i < NBUK) {
        int p = bsum[blockIdx.x] + cursor[i];   // global inclusive prefix
        bp[i + 1] = p;
        cursor[i] = p - counts[i];              // bucket start for scatter
    }
    if (i == 0) bp[0] = 0;
}

// edges packed: {col | (row&1)<<15, val_bits}   (col < 20000 < 2^15)
__global__ void scatter_kernel(const int* __restrict__ rows, const int* __restrict__ cols,
                               const float* __restrict__ vals, int* __restrict__ cursor,
                               int2* __restrict__ edges) {
    int e = blockIdx.x * 256 + threadIdx.x;
    if (e < NNZ_) {
        int c = cols[e];
        int r = rows[e];
        int key = (r >> 1) * NSLICE + c / SLICE_W;
        int pos = atomicAdd(&cursor[key], 1);
        int2 pe;
        pe.x = c | ((r & 1) << 15);
        pe.y = __float_as_int(vals[e]);
        edges[pos] = pe;
    }
}

// ---------------- fat prep: x->X0 bf16 (T layout) + Wfrag pack ----------------
__global__ void prep_kernel(const float* __restrict__ x, uint_t* __restrict__ X0,
                            const float* __restrict__ W, ushort_t* __restrict__ Wfrag) {
    int blk = blockIdx.x;
    if (blk < 20000) {
        int idx = blk * 256 + threadIdx.x;      // over N_V*B_*32
        int f2 = idx & 31;
        int b  = (idx >> 5) & 7;
        int n  = idx >> 8;
        float2 v = *(const float2*)&x[((size_t)b * N_V + n) * F_ + f2 * 2];
        X0[n * 256 + b * 32 + f2] = pack2(v.x, v.y);
    } else {
        int idx = (blk - 20000) * 256 + threadIdx.x;
        if (idx < 12 * 4 * 64 * 8) {
            int j    = idx & 7;
            int lane = (idx >> 3) & 63;
            int ct   = (idx >> 9) & 3;
            int s    = idx >> 11;
            int o     = ct * 16 + (lane & 15);
            int kglob = s * 32 + ((lane >> 4) & 3) * 8 + j;
            Wfrag[idx] = f2bf(W[o * (K_ * F_) + kglob]);
        }
    }
}

// -------- SpMM: 1 row-pair per wave, single contiguous slice-ordered stream, ILP-8 --------
template <bool RECUR>
__global__ __launch_bounds__(256) void cheb_pair(const int* __restrict__ bp,
                                                 const int2* __restrict__ edges,
                                                 const ushort_t* __restrict__ Tprev,
                                                 const ushort_t* __restrict__ Tpp,
                                                 ushort_t* __restrict__ Tout) {
    const int wave = threadIdx.x >> 6, lane = threadIdx.x & 63;
    const int pair = blockIdx.x * 4 + wave;        // 10000 pairs
    const int n0 = pair * 2;
    const int fo = lane * 8;                        // bf16 offset (16B per lane)
    const int st = bp[pair * NSLICE];
    const int en = bp[pair * NSLICE + NSLICE];      // whole pair stream, slice-ordered

    float a0[8], a1[8];
#pragma unroll
    for (int i = 0; i < 8; ++i) { a0[i] = 0.f; a1[i] = 0.f; }

    for (int j = st; j < en; j += 8) {
        int2 E[8];
#pragma unroll
        for (int q = 0; q < 8; ++q) {
            E[q] = edges[min(j + q, en - 1)];
        }
        uint4 u[8];
#pragma unroll
        for (int q = 0; q < 8; ++q) {
            u[q] = *(const uint4*)(Tprev + (size_t)(E[q].x & 0x7FFF) * BF + fo);
        }
#pragma unroll
        for (int q = 0; q < 8; ++q) {
            const float v  = (j + q < en) ? __int_as_float(E[q].y) : 0.f;
            const float p0 = (E[q].x & 0x8000) ? 0.f : v;
            const float p1 = (E[q].x & 0x8000) ? v : 0.f;
            float e[8];
            unpack2(u[q].x, e[0], e[1]); unpack2(u[q].y, e[2], e[3]);
            unpack2(u[q].z, e[4], e[5]); unpack2(u[q].w, e[6], e[7]);
#pragma unroll
            for (int i = 0; i < 8; ++i) {
                a0[i] = fmaf(p0, e[i], a0[i]);
                a1[i] = fmaf(p1, e[i], a1[i]);
            }
        }
    }

    // epilogue: row n0 from a0, row n0+1 from a1
    {
        float res[8];
#pragma unroll
        for (int i = 0; i < 8; ++i) res[i] = a0[i];
        if (RECUR) {
            uint4 up = *(const uint4*)(Tpp + (size_t)n0 * BF + fo);
            float ep[8];
            unpack2(up.x, ep[0], ep[1]); unpack2(up.y, ep[2], ep[3]);
            unpack2(up.z, ep[4], ep[5]); unpack2(up.w, ep[6], ep[7]);
#pragma unroll
            for (int i = 0; i < 8; ++i) res[i] = 2.f * res[i] - ep[i];
        }
        uint4 st4;
        st4.x = pack2(res[0], res[1]);
        st4.y = pack2(res[2], res[3]);
        st4.z = pack2(res[4], res[5]);
        st4.w = pack2(res[6], res[7]);
        *(uint4*)(Tout + (size_t)n0 * BF + fo) = st4;
    }
    {
        float res[8];
#pragma unroll
        for (int i = 0; i < 8; ++i) res[i] = a1[i];
        if (RECUR) {
            uint4 up = *(const uint4*)(Tpp + (size_t)(n0 + 1) * BF + fo);
            float ep[8];
            unpack2(up.x, ep[0], ep[1]); unpack2(up.y, ep[2], ep[3]);
            unpack2(up.z, ep[4], ep[5]); unpack2(up.w, ep[6], ep[7]);
#pragma unroll
            for (int i = 0; i < 8; ++i) res[i] = 2.f * res[i] - ep[i];
        }
        uint4 st4;
        st4.x = pack2(res[0], res[1]);
        st4.y = pack2(res[2], res[3]);
        st4.z = pack2(res[4], res[5]);
        st4.w = pack2(res[6], res[7]);
        *(uint4*)(Tout + (size_t)(n0 + 1) * BF + fo) = st4;
    }
}

// ---------------- FC via MFMA 16x16x32 bf16, 2 tiles/wave ----------------
__global__ __launch_bounds__(256) void fc_mfma(const ushort_t* __restrict__ X0,
                                               const ushort_t* __restrict__ T1,
                                               const ushort_t* __restrict__ T2,
                                               const ushort_t* __restrict__ T3,
                                               const ushort_t* __restrict__ T4,
                                               const ushort_t* __restrict__ T5,
                                               const ushort_t* __restrict__ Wfrag,
                                               const float* __restrict__ bias,
                                               float* __restrict__ out) {
    const int wave = threadIdx.x >> 6, lane = threadIdx.x & 63;
    const int quad = lane >> 4, col = lane & 15;
    const int tb = blockIdx.x * 128 + wave * 32;      // 2 tiles: tb, tb+16
    const int r0 = tb + col, r1 = tb + 16 + col;
    const ushort_t* Tbuf[6] = {X0, T1, T2, T3, T4, T5};

    frag_cd acc0[4], acc1[4];
#pragma unroll
    for (int ct = 0; ct < 4; ++ct) {
        acc0[ct] = (frag_cd){0.f, 0.f, 0.f, 0.f};
        acc1[ct] = (frag_cd){0.f, 0.f, 0.f, 0.f};
    }

#pragma unroll
    for (int s = 0; s < 12; ++s) {
        const int f0 = (s & 1) * 32 + quad * 8;
        frag_ab fa0 = *(const frag_ab*)(Tbuf[s >> 1] + (size_t)r0 * F_ + f0);
        frag_ab fa1 = *(const frag_ab*)(Tbuf[s >> 1] + (size_t)r1 * F_ + f0);
#pragma unroll
        for (int ct = 0; ct < 4; ++ct) {
            frag_ab bfr = *(const frag_ab*)(Wfrag + (((s * 4 + ct) * 64 + lane) << 3));
            acc0[ct] = __builtin_amdgcn_mfma_f32_16x16x32_bf16(fa0, bfr, acc0[ct], 0, 0, 0);
            acc1[ct] = __builtin_amdgcn_mfma_f32_16x16x32_bf16(fa1, bfr, acc1[ct], 0, 0, 0);
        }
    }

    // C/D: col = lane&15, row = quad*4 + reg
#pragma unroll
    for (int ct = 0; ct < 4; ++ct) {
        const int o = ct * 16 + col;
        const float bv = bias[o];
#pragma unroll
        for (int reg = 0; reg < 4; ++reg) {
            int ra = tb + quad * 4 + reg;
            int rb = ra + 16;
            out[(size_t)(ra & 7) * N_V * OUT_ + (size_t)(ra >> 3) * OUT_ + o] = acc0[ct][reg] + bv;
            out[(size_t)(rb & 7) * N_V * OUT_ + (size_t)(rb >> 3) * OUT_ + o] = acc1[ct][reg] + bv;
        }
    }
}

// ---------------- launcher ----------------

extern "C" void kernel_launch(void* const* d_in, const int* in_sizes, int n_in,
                              void* d_out, int out_size, void* d_ws, size_t ws_size,
                              hipStream_t stream) {
    const float* x    = (const float*)d_in[0];
    const int*   rows = (const int*)  d_in[1];
    const int*   cols = (const int*)  d_in[2];
    const float* vals = (const float*)d_in[3];
    const float* W    = (const float*)d_in[4];
    const float* bias = (const float*)d_in[5];
    float* out = (float*)d_out;

    const size_t TSZ = (size_t)N_V * BF;           // bf16 elements per T buffer
    ushort_t* T1 = (ushort_t*)d_ws;
    ushort_t* T2 = T1 + TSZ;
    ushort_t* T3 = T2 + TSZ;
    ushort_t* T4 = T3 + TSZ;
    ushort_t* T5 = T4 + TSZ;
    ushort_t* X0 = T5 + TSZ;
    ushort_t* Wfrag = X0 + TSZ;                    // 24576 ushorts
    int* counts    = (int*)(Wfrag + 24576);        // NBUK
    int* bp        = counts + NBUK;                // NBUK+1 (+pad)
    int* cursor    = bp + NBUK + 64;               // NBUK
    int* bsum      = cursor + NBUK;                // 256
    int2* edges    = (int2*)(bsum + 256);          // NNZ int2

    hipMemsetAsync(counts, 0, NBUK * sizeof(int), stream);
    hist_kernel<<<(NNZ_ + 255) / 256, 256, 0, stream>>>(rows, cols, counts);
    scan1<<<SCANB, 1024, 0, stream>>>(counts, cursor, bsum);
    scan2<<<1, 256, 0, stream>>>(bsum);
    scan3<<<SCANB, 1024, 0, stream>>>(counts, bsum, bp, cursor);
    scatter_kernel<<<(NNZ_ + 255) / 256, 256, 0, stream>>>(rows, cols, vals, cursor, edges);
    prep_kernel<<<20096, 256, 0, stream>>>(x, (uint_t*)X0, W, Wfrag);

    cheb_pair<false><<<NPAIR / 4, 256, 0, stream>>>(bp, edges, X0, nullptr, T1);
    cheb_pair<true ><<<NPAIR / 4, 256, 0, stream>>>(bp, edges, T1, X0, T2);
    cheb_pair<true ><<<NPAIR / 4, 256, 0, stream>>>(bp, edges, T2, T1, T3);
    cheb_pair<true ><<<NPAIR / 4, 256, 0, stream>>>(bp, edges, T3, T2, T4);
    cheb_pair<true ><<<NPAIR / 4, 256, 0, stream>>>(bp, edges, T4, T3, T5);

    fc_mfma<<<(N_V * B_) / 128, 256, 0, stream>>>(X0, T1, T2, T3, T4, T5, Wfrag, bias, out);
}